// Round 1
// baseline (237.189 us; speedup 1.0000x reference)
//
#include <hip/hip_runtime.h>

// x [B,C,H,W] fp32, guide [B,1,H,W] fp32.
// out[b,c,h,t] = max_{j<=t} x[b,c,h,j]*guide[b,0,h,j]  (cummax along W)
#define PB 8
#define PC 256
#define PH 128
#define PW 128
#define TOTAL_ROWS (PB * PC * PH)      // 262144
#define HALF_ROWS  (TOTAL_ROWS / 2)    // 131072

// Native clang vector type — __builtin_nontemporal_* requires this.
typedef float vfloat4 __attribute__((ext_vector_type(4)));

// 16 lanes per row, each lane owns 8 contiguous elems (two float4 quads).
// Each thread processes TWO independent far-apart rows (r, r+HALF_ROWS) for
// MLP/ILP. vs the previous 32-lane/4-elem version this halves the wave
// count, cuts shuffle ops per byte 2.4x (4-step scan over 16 lanes), and
// drops the predicated scan (shfl_up OOB returns own value = fmax identity).
// x/guide loads use the cached path (the 32B-strided quad pairs rely on L1
// read-allocate so the 2nd quad of each lane is an L1 hit); stores are
// non-temporal (pure streaming output, no reuse).
__global__ __launch_bounds__(256) void i5pool_cummax_kernel(
    const float* __restrict__ x,
    const float* __restrict__ guide,
    float* __restrict__ out)
{
    const int tid = blockIdx.x * blockDim.x + threadIdx.x;
    const int sub = tid & 15;          // lane-within-row (owns elems 8*sub..8*sub+7)
    const int r0  = tid >> 4;          // first row, 0..HALF_ROWS-1
    const int r1  = r0 + HALF_ROWS;    // second row (independent work)

    // row = (b*PC + c)*PH + h  ->  guide row = (b*PH + h)
    const int h0 = r0 & (PH - 1);
    const int b0 = r0 >> 15;           // r0 / (PC*PH)
    const int h1 = r1 & (PH - 1);
    const int b1 = r1 >> 15;

    const size_t xoff0 = (size_t)r0 * PW + sub * 8;
    const size_t xoff1 = (size_t)r1 * PW + sub * 8;
    const size_t goff0 = ((size_t)b0 * PH + h0) * PW + sub * 8;
    const size_t goff1 = ((size_t)b1 * PH + h1) * PW + sub * 8;

    const vfloat4* xp0 = (const vfloat4*)(x + xoff0);
    const vfloat4* xp1 = (const vfloat4*)(x + xoff1);
    const vfloat4* gp0 = (const vfloat4*)(guide + goff0);
    const vfloat4* gp1 = (const vfloat4*)(guide + goff1);

    // Issue all loads up front: 4 independent x chains + 4 guide chains.
    vfloat4 xa0 = xp0[0];
    vfloat4 xa1 = xp0[1];
    vfloat4 xb0 = xp1[0];
    vfloat4 xb1 = xp1[1];
    vfloat4 ga0 = gp0[0];
    vfloat4 ga1 = gp0[1];
    vfloat4 gb0 = gp1[0];
    vfloat4 gb1 = gp1[1];

    // --- row 0: local inclusive max-scan over the 8 owned elems ---
    float a0 = xa0.x * ga0.x;
    float a1 = fmaxf(a0, xa0.y * ga0.y);
    float a2 = fmaxf(a1, xa0.z * ga0.z);
    float a3 = fmaxf(a2, xa0.w * ga0.w);
    float a4 = fmaxf(a3, xa1.x * ga1.x);
    float a5 = fmaxf(a4, xa1.y * ga1.y);
    float a6 = fmaxf(a5, xa1.z * ga1.z);
    float a7 = fmaxf(a6, xa1.w * ga1.w);
    // --- row 1 ---
    float c0 = xb0.x * gb0.x;
    float c1 = fmaxf(c0, xb0.y * gb0.y);
    float c2 = fmaxf(c1, xb0.z * gb0.z);
    float c3 = fmaxf(c2, xb0.w * gb0.w);
    float c4 = fmaxf(c3, xb1.x * gb1.x);
    float c5 = fmaxf(c4, xb1.y * gb1.y);
    float c6 = fmaxf(c5, xb1.z * gb1.z);
    float c7 = fmaxf(c6, xb1.w * gb1.w);

    // Interleaved branchless 16-lane inclusive max-scans of lane totals.
    // __shfl_up with src lane below the segment floor returns the caller's
    // own value; fmax(x, x) == x, so no predicate is needed.
    float incA = a7;
    float incC = c7;
    #pragma unroll
    for (int d = 1; d < 16; d <<= 1) {
        float tA = __shfl_up(incA, d, 16);
        float tC = __shfl_up(incC, d, 16);
        incA = fmaxf(incA, tA);
        incC = fmaxf(incC, tC);
    }
    float preA = __shfl_up(incA, 1, 16);
    float preC = __shfl_up(incC, 1, 16);
    if (sub == 0) {                     // compiles to v_cndmask, no branch
        preA = -__builtin_inff();
        preC = -__builtin_inff();
    }
    a0 = fmaxf(a0, preA); a1 = fmaxf(a1, preA);
    a2 = fmaxf(a2, preA); a3 = fmaxf(a3, preA);
    a4 = fmaxf(a4, preA); a5 = fmaxf(a5, preA);
    a6 = fmaxf(a6, preA); a7 = fmaxf(a7, preA);
    c0 = fmaxf(c0, preC); c1 = fmaxf(c1, preC);
    c2 = fmaxf(c2, preC); c3 = fmaxf(c3, preC);
    c4 = fmaxf(c4, preC); c5 = fmaxf(c5, preC);
    c6 = fmaxf(c6, preC); c7 = fmaxf(c7, preC);

    vfloat4* op0 = (vfloat4*)(out + xoff0);
    vfloat4* op1 = (vfloat4*)(out + xoff1);
    vfloat4 oa0 = {a0, a1, a2, a3};
    vfloat4 oa1 = {a4, a5, a6, a7};
    vfloat4 oc0 = {c0, c1, c2, c3};
    vfloat4 oc1 = {c4, c5, c6, c7};
    __builtin_nontemporal_store(oa0, op0);
    __builtin_nontemporal_store(oa1, op0 + 1);
    __builtin_nontemporal_store(oc0, op1);
    __builtin_nontemporal_store(oc1, op1 + 1);
}

extern "C" void kernel_launch(void* const* d_in, const int* in_sizes, int n_in,
                              void* d_out, int out_size, void* d_ws, size_t ws_size,
                              hipStream_t stream) {
    const float* x     = (const float*)d_in[0];
    const float* guide = (const float*)d_in[1];
    float* out = (float*)d_out;

    // HALF_ROWS rows per "pass", 16 lanes per row -> 2,097,152 threads
    const int total_threads = HALF_ROWS * (PW / 8);
    const int block = 256;
    const int grid = total_threads / block;  // 8192

    i5pool_cummax_kernel<<<grid, block, 0, stream>>>(x, guide, out);
}

// Round 2
// 220.528 us; speedup vs baseline: 1.0756x; 1.0756x over previous
//
#include <hip/hip_runtime.h>

// x [B,C,H,W] fp32, guide [B,1,H,W] fp32.
// out[b,c,h,t] = max_{j<=t} x[b,c,h,j]*guide[b,0,h,j]  (cummax along W)
#define PB 8
#define PC 256
#define PH 128
#define PW 128
#define TOTAL_ROWS (PB * PC * PH)      // 262144
#define ROWS_PER_THREAD 4
#define ROW_GROUPS (TOTAL_ROWS / ROWS_PER_THREAD)  // 65536

// Native clang vector type — __builtin_nontemporal_* requires this.
typedef float vfloat4 __attribute__((ext_vector_type(4)));

// Layout: 32 lanes per row, each lane owns one float4 (elems 4*sub..4*sub+3)
// -> every x load / out store instruction is a fully-coalesced contiguous
// 1 KB per wave (lanes 0-31 = row r, lanes 32-63 = row r+1, adjacent in
// memory). Each thread processes FOUR channel-adjacent rows (c..c+3 at the
// same b,h): they share ONE guide row (1 guide load instead of 4) and give
// 4 independent fully-consumed miss streams per thread (Little's law: the
// round-1 kernel sat at 33% BW with VALUBusy 7% -> latency/MLP-bound).
// x loads + out stores are non-temporal (pure streaming, no reuse); guide
// stays on the cached path (reused by 256 channels).
__global__ __launch_bounds__(256, 8) void i5pool_cummax_kernel(
    const float* __restrict__ x,
    const float* __restrict__ guide,
    float* __restrict__ out)
{
    const int tid = blockIdx.x * blockDim.x + threadIdx.x;
    const int sub = tid & 31;          // lane-within-row (owns elems 4*sub..)
    const int rg  = tid >> 5;          // row group, 0..ROW_GROUPS-1

    // rg = (b*64 + c4)*128 + h ; rows are (b*256 + 4*c4 + k)*128 + h
    const int h = rg & (PH - 1);
    const int g = rg >> 7;             // b*64 + c4
    const int b = rg >> 13;

    const size_t row0  = ((size_t)(g << 2)) * PH + h;      // row index, k=0
    const size_t xoff  = row0 * PW + sub * 4;              // k stride = PH*PW
    const size_t goff  = ((size_t)b * PH + h) * PW + sub * 4;

    const vfloat4* xp = (const vfloat4*)(x + xoff);
    vfloat4*       op = (vfloat4*)(out + xoff);
    const size_t kstride = (size_t)PH * PW / 4;            // in vfloat4 units

    // Issue all loads up front: 4 independent NT x streams + 1 cached guide.
    vfloat4 xv[ROWS_PER_THREAD];
    #pragma unroll
    for (int k = 0; k < ROWS_PER_THREAD; ++k)
        xv[k] = __builtin_nontemporal_load(xp + k * kstride);
    const vfloat4 gv = *(const vfloat4*)(guide + goff);

    // Local inclusive max-scan over each lane's 4 elems; tot[k] = lane max.
    vfloat4 ov[ROWS_PER_THREAD];
    float  tot[ROWS_PER_THREAD];
    #pragma unroll
    for (int k = 0; k < ROWS_PER_THREAD; ++k) {
        float e0 = xv[k].x * gv.x;
        float e1 = fmaxf(e0, xv[k].y * gv.y);
        float e2 = fmaxf(e1, xv[k].z * gv.z);
        float e3 = fmaxf(e2, xv[k].w * gv.w);
        ov[k].x = e0; ov[k].y = e1; ov[k].z = e2; ov[k].w = e3;
        tot[k] = e3;
    }

    // Four interleaved branchless 32-lane inclusive max-scans.
    // __shfl_up below the segment floor returns own value; fmax(x,x)==x.
    #pragma unroll
    for (int d = 1; d < 32; d <<= 1) {
        float t0 = __shfl_up(tot[0], d, 32);
        float t1 = __shfl_up(tot[1], d, 32);
        float t2 = __shfl_up(tot[2], d, 32);
        float t3 = __shfl_up(tot[3], d, 32);
        tot[0] = fmaxf(tot[0], t0);
        tot[1] = fmaxf(tot[1], t1);
        tot[2] = fmaxf(tot[2], t2);
        tot[3] = fmaxf(tot[3], t3);
    }

    #pragma unroll
    for (int k = 0; k < ROWS_PER_THREAD; ++k) {
        float pre = __shfl_up(tot[k], 1, 32);
        if (sub == 0) pre = -__builtin_inff();   // v_cndmask, no branch
        ov[k].x = fmaxf(ov[k].x, pre);
        ov[k].y = fmaxf(ov[k].y, pre);
        ov[k].z = fmaxf(ov[k].z, pre);
        ov[k].w = fmaxf(ov[k].w, pre);
    }

    #pragma unroll
    for (int k = 0; k < ROWS_PER_THREAD; ++k)
        __builtin_nontemporal_store(ov[k], op + k * kstride);
}

extern "C" void kernel_launch(void* const* d_in, const int* in_sizes, int n_in,
                              void* d_out, int out_size, void* d_ws, size_t ws_size,
                              hipStream_t stream) {
    const float* x     = (const float*)d_in[0];
    const float* guide = (const float*)d_in[1];
    float* out = (float*)d_out;

    // ROW_GROUPS row-quads, 32 lanes each -> 2,097,152 threads
    const int total_threads = ROW_GROUPS * 32;
    const int block = 256;
    const int grid = total_threads / block;  // 8192

    i5pool_cummax_kernel<<<grid, block, 0, stream>>>(x, guide, out);
}